// Round 1
// baseline (1913.907 us; speedup 1.0000x reference)
//
#include <hip/hip_runtime.h>
#include <math.h>

constexpr int Hd = 1024;
constexpr int Bn = 32;
constexpr int Sn = 2048;
constexpr int Mn = Bn * Sn;     // 65536 rows (b*s)
constexpr int BM = 128, BN = 128, BK = 16;
constexpr int LDT = 136;        // padded LDS row stride (floats); 136*4 = 544 bytes, 16B-aligned rows
constexpr int NXB = Hd / BN;    // 8 column blocks
constexpr int SCH = 8;          // s-chunks for context phase

// ---------------- Phase A: q_proj[b,o] = query[b,:] . Wa_w[o,:] + Wa_b[o] ----------------
// one wave per output; coalesced float4 row reads + shuffle reduce
__global__ __launch_bounds__(256) void qproj_kernel(
    const float* __restrict__ query, const float* __restrict__ Wa_w,
    const float* __restrict__ Wa_b, float* __restrict__ q_proj)
{
    int gtid = blockIdx.x * 256 + threadIdx.x;
    int wid  = gtid >> 6;            // 0..32767, one per (b,o)
    int lane = threadIdx.x & 63;
    int b = wid >> 10, o = wid & 1023;
    const float4* q = reinterpret_cast<const float4*>(query + (size_t)b * Hd);
    const float4* w = reinterpret_cast<const float4*>(Wa_w + (size_t)o * Hd);
    float acc = 0.f;
#pragma unroll
    for (int i = 0; i < 4; ++i) {
        float4 qv = q[lane + i * 64];
        float4 wv = w[lane + i * 64];
        acc = fmaf(qv.x, wv.x, acc);
        acc = fmaf(qv.y, wv.y, acc);
        acc = fmaf(qv.z, wv.z, acc);
        acc = fmaf(qv.w, wv.w, acc);
    }
#pragma unroll
    for (int off = 32; off > 0; off >>= 1) acc += __shfl_down(acc, off);
    if (lane == 0) q_proj[wid] = acc + Wa_b[o];
}

// ---------------- Phase B: fused k_proj GEMM + tanh + Va dot ----------------
// C[bs,o] = keys[bs,:] . Ua_w[o,:]  (both K-contiguous, "NT" layout)
// partial[bs,bx] = sum_{o in block} Va_w[o]*tanh(q_proj[b,o] + Ua_b[o] + C[bs,o])
__global__ __launch_bounds__(256, 2) void score_gemm_kernel(
    const float* __restrict__ keys, const float* __restrict__ Ua_w,
    const float* __restrict__ Ua_b, const float* __restrict__ Va_w,
    const float* __restrict__ q_proj, float* __restrict__ partial)
{
    __shared__ float As[BK][LDT];
    __shared__ float Bs[BK][LDT];
    __shared__ float red[BM][17];
    __shared__ float qpb[BN], uab[BN], vaw[BN];

    const int bx = blockIdx.x;            // 0..NXB-1   (o blocks, fastest -> share A tile in L2)
    const int by = blockIdx.y;            // 0..511     (bs blocks)
    const int tid = threadIdx.x;
    const int tx = tid & 15, ty = tid >> 4;

    const int m0 = by * BM;
    const int n0 = bx * BN;
    const int b  = m0 >> 11;              // BM=128 divides S=2048: whole block in one batch

    const float* Ap = keys + (size_t)m0 * Hd;
    const float* Bp = Ua_w + (size_t)n0 * Hd;

    float acc[8][8] = {};

    for (int k0 = 0; k0 < Hd; k0 += BK) {
        __syncthreads();
#pragma unroll
        for (int u = 0; u < 2; ++u) {
            int f = tid + u * 256;        // 0..511  -> 128 rows x 4 float4
            int row = f >> 2;
            int kq = (f & 3) << 2;
            float4 av = *reinterpret_cast<const float4*>(Ap + (size_t)row * Hd + k0 + kq);
            float4 bv = *reinterpret_cast<const float4*>(Bp + (size_t)row * Hd + k0 + kq);
            As[kq + 0][row] = av.x; As[kq + 1][row] = av.y;
            As[kq + 2][row] = av.z; As[kq + 3][row] = av.w;
            Bs[kq + 0][row] = bv.x; Bs[kq + 1][row] = bv.y;
            Bs[kq + 2][row] = bv.z; Bs[kq + 3][row] = bv.w;
        }
        __syncthreads();
#pragma unroll
        for (int k = 0; k < BK; ++k) {
            float4 a0 = *reinterpret_cast<const float4*>(&As[k][ty * 8]);
            float4 a1 = *reinterpret_cast<const float4*>(&As[k][ty * 8 + 4]);
            float4 b0 = *reinterpret_cast<const float4*>(&Bs[k][tx * 8]);
            float4 b1 = *reinterpret_cast<const float4*>(&Bs[k][tx * 8 + 4]);
            float a[8]  = {a0.x, a0.y, a0.z, a0.w, a1.x, a1.y, a1.z, a1.w};
            float bb[8] = {b0.x, b0.y, b0.z, b0.w, b1.x, b1.y, b1.z, b1.w};
#pragma unroll
            for (int i = 0; i < 8; ++i)
#pragma unroll
                for (int j = 0; j < 8; ++j)
                    acc[i][j] = fmaf(a[i], bb[j], acc[i][j]);
        }
    }

    if (tid < BN) {
        qpb[tid] = q_proj[(size_t)b * Hd + n0 + tid];
        uab[tid] = Ua_b[n0 + tid];
        vaw[tid] = Va_w[n0 + tid];
    }
    __syncthreads();

#pragma unroll
    for (int i = 0; i < 8; ++i) {
        float s = 0.f;
#pragma unroll
        for (int j = 0; j < 8; ++j) {
            int c = tx * 8 + j;
            s = fmaf(vaw[c], tanhf(qpb[c] + uab[c] + acc[i][j]), s);
        }
        red[ty * 8 + i][tx] = s;
    }
    __syncthreads();
    if (tid < BM) {
        float t = 0.f;
#pragma unroll
        for (int j = 0; j < 16; ++j) t += red[tid][j];
        partial[(size_t)(m0 + tid) * NXB + bx] = t;
    }
}

// ---------------- Phase C: reduce partials + softmax over S ----------------
__global__ __launch_bounds__(256) void softmax_kernel(
    const float* __restrict__ partial, const float* __restrict__ Va_b,
    float* __restrict__ weights)
{
    __shared__ float sred[4];
    const int b = blockIdx.x, tid = threadIdx.x;
    const int lane = tid & 63, wv = tid >> 6;
    const float vb = Va_b[0];
    float sc[8];
    float mx = -1e30f;
#pragma unroll
    for (int t = 0; t < 8; ++t) {
        size_t bs = (size_t)b * Sn + t * 256 + tid;
        const float4* p = reinterpret_cast<const float4*>(partial + bs * NXB);
        float4 p0 = p[0], p1 = p[1];
        float v = vb + p0.x + p0.y + p0.z + p0.w + p1.x + p1.y + p1.z + p1.w;
        sc[t] = v;
        mx = fmaxf(mx, v);
    }
#pragma unroll
    for (int off = 32; off > 0; off >>= 1) mx = fmaxf(mx, __shfl_xor(mx, off));
    if (lane == 0) sred[wv] = mx;
    __syncthreads();
    mx = fmaxf(fmaxf(sred[0], sred[1]), fmaxf(sred[2], sred[3]));
    __syncthreads();
    float sum = 0.f;
#pragma unroll
    for (int t = 0; t < 8; ++t) { sc[t] = expf(sc[t] - mx); sum += sc[t]; }
#pragma unroll
    for (int off = 32; off > 0; off >>= 1) sum += __shfl_xor(sum, off);
    if (lane == 0) sred[wv] = sum;
    __syncthreads();
    sum = sred[0] + sred[1] + sred[2] + sred[3];
    float inv = 1.0f / sum;
#pragma unroll
    for (int t = 0; t < 8; ++t)
        weights[(size_t)b * Sn + t * 256 + tid] = sc[t] * inv;
}

// ---------------- Phase D: context[b,h] = sum_s w[b,s]*keys[b,s,h] ----------------
__global__ __launch_bounds__(256) void context_partial_kernel(
    const float* __restrict__ keys, const float* __restrict__ weights,
    float* __restrict__ cpart)
{
    __shared__ float w[256];
    const int b = blockIdx.x, hb = blockIdx.y, sc = blockIdx.z;
    const int h = hb * 256 + threadIdx.x;
    w[threadIdx.x] = weights[(size_t)b * Sn + sc * 256 + threadIdx.x];
    __syncthreads();
    const float* kp = keys + ((size_t)b * Sn + sc * 256) * Hd + h;
    float acc = 0.f;
#pragma unroll 8
    for (int s = 0; s < 256; ++s)
        acc = fmaf(w[s], kp[(size_t)s * Hd], acc);
    cpart[(size_t)(b * SCH + sc) * Hd + h] = acc;
}

__global__ __launch_bounds__(256) void context_reduce_kernel(
    const float* __restrict__ cpart, float* __restrict__ ctx)
{
    int idx = blockIdx.x * 256 + threadIdx.x;   // 0..32767
    int b = idx >> 10, h = idx & 1023;
    float t = 0.f;
#pragma unroll
    for (int s = 0; s < SCH; ++s) t += cpart[(size_t)(b * SCH + s) * Hd + h];
    ctx[idx] = t;
}

extern "C" void kernel_launch(void* const* d_in, const int* in_sizes, int n_in,
                              void* d_out, int out_size, void* d_ws, size_t ws_size,
                              hipStream_t stream)
{
    const float* query = (const float*)d_in[0];
    const float* keys  = (const float*)d_in[1];
    const float* Wa_w  = (const float*)d_in[2];
    const float* Wa_b  = (const float*)d_in[3];
    const float* Ua_w  = (const float*)d_in[4];
    const float* Ua_b  = (const float*)d_in[5];
    const float* Va_w  = (const float*)d_in[6];
    const float* Va_b  = (const float*)d_in[7];

    float* ctx     = (float*)d_out;            // context: 32*1024
    float* weights = (float*)d_out + Bn * Hd;  // weights: 32*2048

    float* ws      = (float*)d_ws;
    float* q_proj  = ws;                       // 32768 floats
    float* partial = ws + 32768;               // 65536*8 = 524288 floats
    float* cpart   = ws + 32768 + 524288;      // 32*8*1024 = 262144 floats

    qproj_kernel<<<dim3(8192), dim3(256), 0, stream>>>(query, Wa_w, Wa_b, q_proj);
    score_gemm_kernel<<<dim3(NXB, Mn / BM), dim3(256), 0, stream>>>(
        keys, Ua_w, Ua_b, Va_w, q_proj, partial);
    softmax_kernel<<<dim3(Bn), dim3(256), 0, stream>>>(partial, Va_b, weights);
    context_partial_kernel<<<dim3(Bn, Hd / 256, SCH), dim3(256), 0, stream>>>(
        keys, weights, cpart);
    context_reduce_kernel<<<dim3(Mn / Sn * 4 /* 128 */), dim3(256), 0, stream>>>(cpart, ctx);
}

// Round 3
// 776.672 us; speedup vs baseline: 2.4642x; 2.4642x over previous
//
#include <hip/hip_runtime.h>
#include <math.h>

typedef __attribute__((ext_vector_type(8))) short short8;
typedef __attribute__((ext_vector_type(4))) float f32x4;
typedef unsigned int u32;

constexpr int Hd = 1024;
constexpr int Bn = 32;
constexpr int Sn = 2048;
constexpr int Mn = Bn * Sn;     // 65536
constexpr int NXB = 8;          // 1024/128 column blocks
constexpr int SCH = 8;          // s-chunks for context phase

// workspace layout (bytes)
constexpr size_t WS_QPROJ   = 0;                      // 32768 floats  (128 KB)
constexpr size_t WS_PARTIAL = 131072;                 // 524288 floats (2 MiB)
constexpr size_t WS_CPART   = 131072 + 2097152;       // 262144 floats (1 MiB)
constexpr size_t WS_BASE_END = WS_CPART + 1048576;    // 3,276,800 B (round-1 proven)
constexpr size_t WS_UAHI    = WS_BASE_END;            // 2 MiB
constexpr size_t WS_UALO    = WS_BASE_END + 2097152;  // 2 MiB
constexpr size_t WS_NEED_SPLIT = WS_UALO + 2097152;   // 7,471,104 B

__device__ __forceinline__ void gload16(const void* g, void* l) {
    __builtin_amdgcn_global_load_lds(
        (const __attribute__((address_space(1))) u32*)g,
        (__attribute__((address_space(3))) u32*)l, 16, 0, 0);
}

__device__ __forceinline__ void split4(float4 v, uint2& h, uint2& l) {
    u32 b0 = __float_as_uint(v.x), b1 = __float_as_uint(v.y);
    u32 b2 = __float_as_uint(v.z), b3 = __float_as_uint(v.w);
    h.x = (b0 >> 16) | (b1 & 0xffff0000u);
    h.y = (b2 >> 16) | (b3 & 0xffff0000u);
    float l0 = v.x - __uint_as_float(b0 & 0xffff0000u);
    float l1 = v.y - __uint_as_float(b1 & 0xffff0000u);
    float l2 = v.z - __uint_as_float(b2 & 0xffff0000u);
    float l3 = v.w - __uint_as_float(b3 & 0xffff0000u);
    l.x = (__float_as_uint(l0) >> 16) | (__float_as_uint(l1) & 0xffff0000u);
    l.y = (__float_as_uint(l2) >> 16) | (__float_as_uint(l3) & 0xffff0000u);
}

// ---------------- split Ua_w (fp32) -> bf16 hi/lo (truncation split) ----------------
__global__ __launch_bounds__(256) void split_kernel(
    const float4* __restrict__ src, uint2* __restrict__ hi, uint2* __restrict__ lo, int n4)
{
    int i = blockIdx.x * 256 + threadIdx.x;
    if (i >= n4) return;
    uint2 h, l;
    split4(src[i], h, l);
    hi[i] = h; lo[i] = l;
}

// ---------------- q_proj[b,o] = query[b,:] . Wa_w[o,:] + Wa_b[o] ----------------
__global__ __launch_bounds__(256) void qproj_kernel(
    const float* __restrict__ query, const float* __restrict__ Wa_w,
    const float* __restrict__ Wa_b, float* __restrict__ q_proj)
{
    int gtid = blockIdx.x * 256 + threadIdx.x;
    int wid  = gtid >> 6;            // one wave per (b,o)
    int lane = threadIdx.x & 63;
    int b = wid >> 10, o = wid & 1023;
    const float4* q = reinterpret_cast<const float4*>(query + (size_t)b * Hd);
    const float4* w = reinterpret_cast<const float4*>(Wa_w + (size_t)o * Hd);
    float acc = 0.f;
#pragma unroll
    for (int i = 0; i < 4; ++i) {
        float4 qv = q[lane + i * 64];
        float4 wv = w[lane + i * 64];
        acc = fmaf(qv.x, wv.x, acc);
        acc = fmaf(qv.y, wv.y, acc);
        acc = fmaf(qv.z, wv.z, acc);
        acc = fmaf(qv.w, wv.w, acc);
    }
#pragma unroll
    for (int off = 32; off > 0; off >>= 1) acc += __shfl_down(acc, off);
    if (lane == 0) q_proj[wid] = acc + Wa_b[o];
}

// ---------------- fused k_proj MFMA GEMM (bf16 hi/lo split) + tanh + Va dot ----------------
// C[m,n] = sum_k keys[m,k] * Ua_w[n,k] via 3-term bf16 split MFMA (hi*hi + hi*lo + lo*hi).
// partial[m,bx] = sum_{n in block} Va_w[n] * tanh(q_proj[b,n] + Ua_b[n] + C[m,n])
// SPLITB=true : B pre-split in ws, staged via global_load_lds (fast path)
// SPLITB=false: B fp32 reg-staged + converted in-kernel (no extra ws)
template <bool SPLITB>
__global__ __launch_bounds__(256, 2) void score_gemm_kernel(
    const float* __restrict__ keys,
    const unsigned short* __restrict__ ua_hi, const unsigned short* __restrict__ ua_lo,
    const float* __restrict__ Ua_w,
    const float* __restrict__ Ua_b, const float* __restrict__ Va_w,
    const float* __restrict__ q_proj, float* __restrict__ partial)
{
    __shared__ __align__(16) unsigned char lds[32768];
    __shared__ float red[128][2];
    constexpr int AHI = 0, ALO = 8192, BHI = 16384, BLO = 24576;

    // XCD-grouped swizzle: wg i -> XCD i%8; the 8 consecutive blocks on one XCD
    // share one A (keys) tile while cycling bx.
    const int id = blockIdx.x;
    const int by = (id & 7) * 64 + (id >> 6);   // 0..511
    const int bx = (id >> 3) & 7;               // 0..7

    const int tid = threadIdx.x;
    const int lane = tid & 63, wid = tid >> 6;
    const int wm = wid >> 1, wn = wid & 1;      // 2x2 wave grid, 64x64 per wave
    const int lr = lane & 15, lk = lane >> 4;
    const int m0 = by * 128, n0 = bx * 128;

    const float* Ap = keys + (size_t)m0 * Hd;
    const float* Bp = Ua_w + (size_t)n0 * Hd;
    const int ar = tid >> 3, ac = tid & 7;      // staging: rows ar+u*32, float4-col ac

    float4 curA[4], nxtA[4], curB[4], nxtB[4];
#pragma unroll
    for (int u = 0; u < 4; ++u)
        curA[u] = *reinterpret_cast<const float4*>(Ap + (size_t)(ar + u * 32) * Hd + ac * 4);
    if (!SPLITB) {
#pragma unroll
        for (int u = 0; u < 4; ++u)
            curB[u] = *reinterpret_cast<const float4*>(Bp + (size_t)(ar + u * 32) * Hd + ac * 4);
    }

    f32x4 acc[4][4];
#pragma unroll
    for (int i = 0; i < 4; ++i)
#pragma unroll
        for (int j = 0; j < 4; ++j) acc[i][j] = f32x4{0.f, 0.f, 0.f, 0.f};

    const char* uah = (const char*)ua_hi;
    const char* ual = (const char*)ua_lo;
    const int c2 = wid * 2;                      // this wave's B chunk pair (SPLITB path)
    const int brow = c2 * 16 + (lane >> 2);
    const size_t boff0 = (size_t)(n0 + brow) * (Hd * 2) + (size_t)(lane & 3) * 16;
    const size_t brstep = (size_t)16 * Hd * 2;

    for (int t = 0; t < 32; ++t) {
        const int k0 = t * 32;
        __syncthreads();                         // previous tile fully consumed
        if (SPLITB) {
            // B tiles: global_load_lds, 16B/lane, linear dest (contiguous 64B rows)
            size_t bo = boff0 + (size_t)k0 * 2;
            gload16(uah + bo, lds + BHI + c2 * 1024);
            gload16(ual + bo, lds + BLO + c2 * 1024);
            gload16(uah + bo + brstep, lds + BHI + (c2 + 1) * 1024);
            gload16(ual + bo + brstep, lds + BLO + (c2 + 1) * 1024);
        } else {
#pragma unroll
            for (int u = 0; u < 4; ++u) {
                uint2 h, l;
                split4(curB[u], h, l);
                int db = (ar + u * 32) * 64 + ac * 8;
                *reinterpret_cast<uint2*>(lds + BHI + db) = h;
                *reinterpret_cast<uint2*>(lds + BLO + db) = l;
            }
        }
        // A tile: convert fp32 -> bf16 hi/lo, write to LDS (contiguous 8B per thread)
#pragma unroll
        for (int u = 0; u < 4; ++u) {
            uint2 h, l;
            split4(curA[u], h, l);
            int db = (ar + u * 32) * 64 + ac * 8;
            *reinterpret_cast<uint2*>(lds + AHI + db) = h;
            *reinterpret_cast<uint2*>(lds + ALO + db) = l;
        }
        __syncthreads();                         // tile ready (barrier drains gload_lds)
        // prefetch for t+1: HBM latency hides under the MFMA phase below
        if (t < 31) {
#pragma unroll
            for (int u = 0; u < 4; ++u)
                nxtA[u] = *reinterpret_cast<const float4*>(
                    Ap + (size_t)(ar + u * 32) * Hd + (k0 + 32) + ac * 4);
            if (!SPLITB) {
#pragma unroll
                for (int u = 0; u < 4; ++u)
                    nxtB[u] = *reinterpret_cast<const float4*>(
                        Bp + (size_t)(ar + u * 32) * Hd + (k0 + 32) + ac * 4);
            }
        }
        // fragments: each ds_read_b128 wave-access is a contiguous 1 KiB -> conflict-free
        short8 ah[4], al[4], bh[4], bl[4];
#pragma unroll
        for (int i = 0; i < 4; ++i) {
            int ab = (wm * 64 + i * 16 + lr) * 64 + lk * 16;
            ah[i] = *reinterpret_cast<const short8*>(lds + AHI + ab);
            al[i] = *reinterpret_cast<const short8*>(lds + ALO + ab);
        }
#pragma unroll
        for (int j = 0; j < 4; ++j) {
            int bb = (wn * 64 + j * 16 + lr) * 64 + lk * 16;
            bh[j] = *reinterpret_cast<const short8*>(lds + BHI + bb);
            bl[j] = *reinterpret_cast<const short8*>(lds + BLO + bb);
        }
#pragma unroll
        for (int i = 0; i < 4; ++i)
#pragma unroll
            for (int j = 0; j < 4; ++j) {
                acc[i][j] = __builtin_amdgcn_mfma_f32_16x16x32_bf16(ah[i], bh[j], acc[i][j], 0, 0, 0);
                acc[i][j] = __builtin_amdgcn_mfma_f32_16x16x32_bf16(ah[i], bl[j], acc[i][j], 0, 0, 0);
                acc[i][j] = __builtin_amdgcn_mfma_f32_16x16x32_bf16(al[i], bh[j], acc[i][j], 0, 0, 0);
            }
        if (t < 31) {
#pragma unroll
            for (int u = 0; u < 4; ++u) curA[u] = nxtA[u];
            if (!SPLITB) {
#pragma unroll
                for (int u = 0; u < 4; ++u) curB[u] = nxtB[u];
            }
        }
    }

    // epilogue: tanh + Va dot + row reduction
    // C/D layout (m89/m91-verified): col = lane&15, row = (lane>>4)*4 + reg
    float vaw_[4], qb_[4], ub_[4];
    const int b = m0 >> 11;
#pragma unroll
    for (int j = 0; j < 4; ++j) {
        int c = n0 + wn * 64 + j * 16 + lr;
        vaw_[j] = Va_w[c];
        qb_[j]  = q_proj[b * Hd + c];
        ub_[j]  = Ua_b[c];
    }
#pragma unroll
    for (int i = 0; i < 4; ++i) {
#pragma unroll
        for (int r = 0; r < 4; ++r) {
            float s = 0.f;
#pragma unroll
            for (int j = 0; j < 4; ++j)
                s = fmaf(vaw_[j], tanhf(qb_[j] + ub_[j] + acc[i][j][r]), s);
#pragma unroll
            for (int m = 1; m < 16; m <<= 1) s += __shfl_xor(s, m);
            if (lr == 0) red[wm * 64 + i * 16 + lk * 4 + r][wn] = s;
        }
    }
    __syncthreads();
    if (tid < 128)
        partial[(size_t)(m0 + tid) * NXB + bx] = red[tid][0] + red[tid][1];
}

// ---------------- reduce partials + softmax over S ----------------
__global__ __launch_bounds__(256) void softmax_kernel(
    const float* __restrict__ partial, const float* __restrict__ Va_b,
    float* __restrict__ weights)
{
    __shared__ float sred[4];
    const int b = blockIdx.x, tid = threadIdx.x;
    const int lane = tid & 63, wv = tid >> 6;
    const float vb = Va_b[0];
    float sc[8];
    float mx = -1e30f;
#pragma unroll
    for (int t = 0; t < 8; ++t) {
        size_t bs = (size_t)b * Sn + t * 256 + tid;
        const float4* p = reinterpret_cast<const float4*>(partial + bs * NXB);
        float4 p0 = p[0], p1 = p[1];
        float v = vb + p0.x + p0.y + p0.z + p0.w + p1.x + p1.y + p1.z + p1.w;
        sc[t] = v;
        mx = fmaxf(mx, v);
    }
#pragma unroll
    for (int off = 32; off > 0; off >>= 1) mx = fmaxf(mx, __shfl_xor(mx, off));
    if (lane == 0) sred[wv] = mx;
    __syncthreads();
    mx = fmaxf(fmaxf(sred[0], sred[1]), fmaxf(sred[2], sred[3]));
    __syncthreads();
    float sum = 0.f;
#pragma unroll
    for (int t = 0; t < 8; ++t) { sc[t] = expf(sc[t] - mx); sum += sc[t]; }
#pragma unroll
    for (int off = 32; off > 0; off >>= 1) sum += __shfl_xor(sum, off);
    if (lane == 0) sred[wv] = sum;
    __syncthreads();
    sum = sred[0] + sred[1] + sred[2] + sred[3];
    float inv = 1.0f / sum;
#pragma unroll
    for (int t = 0; t < 8; ++t)
        weights[(size_t)b * Sn + t * 256 + tid] = sc[t] * inv;
}

// ---------------- context[b,h] = sum_s w[b,s]*keys[b,s,h] ----------------
__global__ __launch_bounds__(256) void context_partial_kernel(
    const float* __restrict__ keys, const float* __restrict__ weights,
    float* __restrict__ cpart)
{
    __shared__ float w[256];
    const int b = blockIdx.x, hb = blockIdx.y, sc = blockIdx.z;
    const int h = hb * 256 + threadIdx.x;
    w[threadIdx.x] = weights[(size_t)b * Sn + sc * 256 + threadIdx.x];
    __syncthreads();
    const float* kp = keys + ((size_t)b * Sn + sc * 256) * Hd + h;
    float acc = 0.f;
#pragma unroll 8
    for (int s = 0; s < 256; ++s)
        acc = fmaf(w[s], kp[(size_t)s * Hd], acc);
    cpart[(size_t)(b * SCH + sc) * Hd + h] = acc;
}

__global__ __launch_bounds__(256) void context_reduce_kernel(
    const float* __restrict__ cpart, float* __restrict__ ctx)
{
    int idx = blockIdx.x * 256 + threadIdx.x;   // 0..32767
    int b = idx >> 10, h = idx & 1023;
    float t = 0.f;
#pragma unroll
    for (int s = 0; s < SCH; ++s) t += cpart[(size_t)(b * SCH + s) * Hd + h];
    ctx[idx] = t;
}

extern "C" void kernel_launch(void* const* d_in, const int* in_sizes, int n_in,
                              void* d_out, int out_size, void* d_ws, size_t ws_size,
                              hipStream_t stream)
{
    const float* query = (const float*)d_in[0];
    const float* keys  = (const float*)d_in[1];
    const float* Wa_w  = (const float*)d_in[2];
    const float* Wa_b  = (const float*)d_in[3];
    const float* Ua_w  = (const float*)d_in[4];
    const float* Ua_b  = (const float*)d_in[5];
    const float* Va_w  = (const float*)d_in[6];
    const float* Va_b  = (const float*)d_in[7];

    float* ctx     = (float*)d_out;            // context: 32*1024
    float* weights = (float*)d_out + Bn * Hd;  // weights: 32*2048

    char* wsb      = (char*)d_ws;
    float* q_proj  = (float*)(wsb + WS_QPROJ);
    float* partial = (float*)(wsb + WS_PARTIAL);
    float* cpart   = (float*)(wsb + WS_CPART);
    unsigned short* ua_hi = (unsigned short*)(wsb + WS_UAHI);
    unsigned short* ua_lo = (unsigned short*)(wsb + WS_UALO);

    const bool use_split = (ws_size >= WS_NEED_SPLIT);  // constant per harness run

    if (use_split)
        split_kernel<<<dim3(1024), dim3(256), 0, stream>>>(
            (const float4*)Ua_w, (uint2*)ua_hi, (uint2*)ua_lo, (Hd * Hd) / 4);
    qproj_kernel<<<dim3(8192), dim3(256), 0, stream>>>(query, Wa_w, Wa_b, q_proj);
    if (use_split)
        score_gemm_kernel<true><<<dim3(4096), dim3(256), 0, stream>>>(
            keys, ua_hi, ua_lo, Ua_w, Ua_b, Va_w, q_proj, partial);
    else
        score_gemm_kernel<false><<<dim3(4096), dim3(256), 0, stream>>>(
            keys, ua_hi, ua_lo, Ua_w, Ua_b, Va_w, q_proj, partial);
    softmax_kernel<<<dim3(Bn), dim3(256), 0, stream>>>(partial, Va_b, weights);
    context_partial_kernel<<<dim3(Bn, Hd / 256, SCH), dim3(256), 0, stream>>>(
        keys, weights, cpart);
    context_reduce_kernel<<<dim3(128), dim3(256), 0, stream>>>(cpart, ctx);
}

// Round 4
// 769.091 us; speedup vs baseline: 2.4885x; 1.0099x over previous
//
#include <hip/hip_runtime.h>
#include <math.h>

typedef __attribute__((ext_vector_type(8))) short short8;
typedef __attribute__((ext_vector_type(4))) float f32x4;
typedef unsigned int u32;

constexpr int Hd = 1024;
constexpr int Bn = 32;
constexpr int Sn = 2048;
constexpr int Mn = 65536;       // B*S rows
constexpr int NXB = 4;          // 1024/256 column blocks
constexpr int SCH = 8;          // s-chunks for context phase

// workspace layout (bytes)
constexpr size_t WS_QPROJ   = 0;                      // 32768 floats (128 KB)
constexpr size_t WS_PARTIAL = 131072;                 // 65536*4 floats (1 MiB)
constexpr size_t WS_CPART   = 131072 + 1048576;       // 262144 floats (1 MiB)
constexpr size_t WS_BASE_END = WS_CPART + 1048576;    // 2,228,224 B
constexpr size_t WS_UAHI    = WS_BASE_END;            // 2 MiB
constexpr size_t WS_UALO    = WS_UAHI + 2097152;      // 2 MiB
constexpr size_t WS_NEED_SPLIT = WS_UALO + 2097152;   // 6,422,528 B

__device__ __forceinline__ void gload16(const void* g, void* l) {
    __builtin_amdgcn_global_load_lds(
        (const __attribute__((address_space(1))) u32*)g,
        (__attribute__((address_space(3))) u32*)l, 16, 0, 0);
}

__device__ __forceinline__ void split4(float4 v, uint2& h, uint2& l) {
    u32 b0 = __float_as_uint(v.x), b1 = __float_as_uint(v.y);
    u32 b2 = __float_as_uint(v.z), b3 = __float_as_uint(v.w);
    h.x = (b0 >> 16) | (b1 & 0xffff0000u);
    h.y = (b2 >> 16) | (b3 & 0xffff0000u);
    float l0 = v.x - __uint_as_float(b0 & 0xffff0000u);
    float l1 = v.y - __uint_as_float(b1 & 0xffff0000u);
    float l2 = v.z - __uint_as_float(b2 & 0xffff0000u);
    float l3 = v.w - __uint_as_float(b3 & 0xffff0000u);
    l.x = (__float_as_uint(l0) >> 16) | (__float_as_uint(l1) & 0xffff0000u);
    l.y = (__float_as_uint(l2) >> 16) | (__float_as_uint(l3) & 0xffff0000u);
}

// ---------------- split Ua_w (fp32) -> bf16 hi/lo ----------------
__global__ __launch_bounds__(256) void split_kernel(
    const float4* __restrict__ src, uint2* __restrict__ hi, uint2* __restrict__ lo, int n4)
{
    int i = blockIdx.x * 256 + threadIdx.x;
    if (i >= n4) return;
    uint2 h, l;
    split4(src[i], h, l);
    hi[i] = h; lo[i] = l;
}

// ---------------- q_proj[b,o] = query[b,:] . Wa_w[o,:] + Wa_b[o] ----------------
__global__ __launch_bounds__(256) void qproj_kernel(
    const float* __restrict__ query, const float* __restrict__ Wa_w,
    const float* __restrict__ Wa_b, float* __restrict__ q_proj)
{
    int gtid = blockIdx.x * 256 + threadIdx.x;
    int wid  = gtid >> 6;            // one wave per (b,o)
    int lane = threadIdx.x & 63;
    int b = wid >> 10, o = wid & 1023;
    const float4* q = reinterpret_cast<const float4*>(query + (size_t)b * Hd);
    const float4* w = reinterpret_cast<const float4*>(Wa_w + (size_t)o * Hd);
    float acc = 0.f;
#pragma unroll
    for (int i = 0; i < 4; ++i) {
        float4 qv = q[lane + i * 64];
        float4 wv = w[lane + i * 64];
        acc = fmaf(qv.x, wv.x, acc);
        acc = fmaf(qv.y, wv.y, acc);
        acc = fmaf(qv.z, wv.z, acc);
        acc = fmaf(qv.w, wv.w, acc);
    }
#pragma unroll
    for (int off = 32; off > 0; off >>= 1) acc += __shfl_down(acc, off);
    if (lane == 0) q_proj[wid] = acc + Wa_b[o];
}

// ---------------- fused k_proj MFMA GEMM (bf16 hi/lo) + tanh + Va dot ----------------
// BM=128 x BN=256 x BK=32; 2x2 waves, each wave 64x128, acc[4][8].
// 96 MFMA / K-step / wave vs ~130 VALU -> MFMA-bound (round3 was 48:110, balanced).
template <bool SPLITB>
__global__ __launch_bounds__(256, 2) void score_gemm_kernel(
    const float* __restrict__ keys,
    const unsigned short* __restrict__ ua_hi, const unsigned short* __restrict__ ua_lo,
    const float* __restrict__ Ua_w,
    const float* __restrict__ Ua_b, const float* __restrict__ Va_w,
    const float* __restrict__ q_proj, float* __restrict__ partial)
{
    __shared__ __align__(16) unsigned char lds[49152];
    __shared__ float red[128][2];
    constexpr int AHI = 0, ALO = 8192, BHI = 16384, BLO = 32768;

    // bijective XCD-grouped swizzle: id = [s:6][bx:2][xcd:3]; 4 consecutive
    // blocks on one XCD share one keys-tile (by) while cycling bx.
    const int id = blockIdx.x;                  // 0..2047
    const int by = (id & 7) * 64 + (id >> 5);   // 0..511
    const int bx = (id >> 3) & 3;               // 0..3

    const int tid = threadIdx.x;
    const int lane = tid & 63, wid = tid >> 6;
    const int wm = wid >> 1, wn = wid & 1;      // 2x2 wave grid
    const int lr = lane & 15, lk = lane >> 4;
    const int m0 = by * 128, n0 = bx * 256;

    const float* Ap = keys + (size_t)m0 * Hd;
    const int ra = tid >> 2, ca = tid & 3;      // A: rows ra+u*64, 16B-slot ca (8 floats)

    float4 curA[4], nxtA[4];
#pragma unroll
    for (int u = 0; u < 2; ++u)
#pragma unroll
        for (int v = 0; v < 2; ++v)
            curA[u * 2 + v] = *reinterpret_cast<const float4*>(
                Ap + (size_t)(ra + u * 64) * Hd + ca * 8 + v * 4);

    f32x4 acc[4][8];
#pragma unroll
    for (int i = 0; i < 4; ++i)
#pragma unroll
        for (int j = 0; j < 8; ++j) acc[i][j] = f32x4{0.f, 0.f, 0.f, 0.f};

    const char* uah = (const char*)ua_hi;
    const char* ual = (const char*)ua_lo;
    const int grow = wid * 16 + (lane >> 2);     // B global row within tile (per u)
    const int gcol = (lane & 3) * 16;            // B global k-byte slot

    for (int t = 0; t < 32; ++t) {
        const int k0 = t * 32;
        __syncthreads();                         // previous tile fully consumed
        if (SPLITB) {
            // B hi/lo: 8x global_load_lds dwordx4, linear LDS dest (lane*16)
#pragma unroll
            for (int u = 0; u < 4; ++u) {
                size_t bo = ((size_t)(n0 + grow + u * 64) << 11) + (size_t)k0 * 2 + gcol;
                gload16(uah + bo, lds + BHI + u * 4096 + wid * 1024);
                gload16(ual + bo, lds + BLO + u * 4096 + wid * 1024);
            }
        } else {
            // fallback: load fp32 B, split in-kernel (latency exposed; correctness path)
#pragma unroll
            for (int u = 0; u < 4; ++u) {
                int s = tid + u * 256, rb = s >> 2, cs = s & 3;
                const float* src = Ua_w + (size_t)(n0 + rb) * Hd + k0 + cs * 8;
                float4 v0 = *reinterpret_cast<const float4*>(src);
                float4 v1 = *reinterpret_cast<const float4*>(src + 4);
                uint2 h0, l0, h1, l1;
                split4(v0, h0, l0); split4(v1, h1, l1);
                uint4 H = {h0.x, h0.y, h1.x, h1.y};
                uint4 L = {l0.x, l0.y, l1.x, l1.y};
                int db = rb * 64 + cs * 16;
                *reinterpret_cast<uint4*>(lds + BHI + db) = H;
                *reinterpret_cast<uint4*>(lds + BLO + db) = L;
            }
        }
        // A: convert fp32 -> hi/lo, ds_write_b128 at lane*16-linear offsets (conflict-free)
#pragma unroll
        for (int u = 0; u < 2; ++u) {
            uint2 h0, l0, h1, l1;
            split4(curA[u * 2], h0, l0); split4(curA[u * 2 + 1], h1, l1);
            uint4 H = {h0.x, h0.y, h1.x, h1.y};
            uint4 L = {l0.x, l0.y, l1.x, l1.y};
            int db = (ra + u * 64) * 64 + ca * 16;
            *reinterpret_cast<uint4*>(lds + AHI + db) = H;
            *reinterpret_cast<uint4*>(lds + ALO + db) = L;
        }
        __syncthreads();                         // tile ready (drains gload_lds + ds_writes)
        // A prefetch for t+1: lands during the MFMA phase, waited at next barrier
        if (t < 31) {
#pragma unroll
            for (int u = 0; u < 2; ++u)
#pragma unroll
                for (int v = 0; v < 2; ++v)
                    nxtA[u * 2 + v] = *reinterpret_cast<const float4*>(
                        Ap + (size_t)(ra + u * 64) * Hd + (k0 + 32) + ca * 8 + v * 4);
        }
        short8 ah[4], al[4];
#pragma unroll
        for (int i = 0; i < 4; ++i) {
            int ab = (wm * 64 + i * 16 + lr) * 64 + lk * 16;
            ah[i] = *reinterpret_cast<const short8*>(lds + AHI + ab);
            al[i] = *reinterpret_cast<const short8*>(lds + ALO + ab);
        }
#pragma unroll
        for (int j = 0; j < 8; ++j) {
            int bb = (wn * 128 + j * 16 + lr) * 64 + lk * 16;
            short8 bh = *reinterpret_cast<const short8*>(lds + BHI + bb);
            short8 bl = *reinterpret_cast<const short8*>(lds + BLO + bb);
#pragma unroll
            for (int i = 0; i < 4; ++i) {
                acc[i][j] = __builtin_amdgcn_mfma_f32_16x16x32_bf16(ah[i], bh, acc[i][j], 0, 0, 0);
                acc[i][j] = __builtin_amdgcn_mfma_f32_16x16x32_bf16(ah[i], bl, acc[i][j], 0, 0, 0);
                acc[i][j] = __builtin_amdgcn_mfma_f32_16x16x32_bf16(al[i], bh, acc[i][j], 0, 0, 0);
            }
        }
        if (t < 31) {
#pragma unroll
            for (int u = 0; u < 4; ++u) curA[u] = nxtA[u];
        }
    }

    // epilogue: tanh + Va dot + row reduction
    // C/D layout (m89/m91): col = lane&15 (n), row = (lane>>4)*4 + reg (m)
    const int b = m0 >> 11;
    float vaw_[8], qb_[8], ub_[8];
#pragma unroll
    for (int j = 0; j < 8; ++j) {
        int c = n0 + wn * 128 + j * 16 + lr;
        vaw_[j] = Va_w[c];
        qb_[j]  = q_proj[b * Hd + c];
        ub_[j]  = Ua_b[c];
    }
#pragma unroll
    for (int i = 0; i < 4; ++i) {
#pragma unroll
        for (int r = 0; r < 4; ++r) {
            float s = 0.f;
#pragma unroll
            for (int j = 0; j < 8; ++j)
                s = fmaf(vaw_[j], tanhf(qb_[j] + ub_[j] + acc[i][j][r]), s);
#pragma unroll
            for (int m = 1; m < 16; m <<= 1) s += __shfl_xor(s, m);
            if (lr == 0) red[wm * 64 + i * 16 + lk * 4 + r][wn] = s;
        }
    }
    __syncthreads();
    if (tid < 128)
        partial[(size_t)(m0 + tid) * NXB + bx] = red[tid][0] + red[tid][1];
}

// ---------------- reduce partials + softmax over S ----------------
__global__ __launch_bounds__(256) void softmax_kernel(
    const float* __restrict__ partial, const float* __restrict__ Va_b,
    float* __restrict__ weights)
{
    __shared__ float sred[4];
    const int b = blockIdx.x, tid = threadIdx.x;
    const int lane = tid & 63, wv = tid >> 6;
    const float vb = Va_b[0];
    float sc[8];
    float mx = -1e30f;
#pragma unroll
    for (int t = 0; t < 8; ++t) {
        size_t bs = (size_t)b * Sn + t * 256 + tid;
        float4 p0 = *reinterpret_cast<const float4*>(partial + bs * NXB);
        float v = vb + p0.x + p0.y + p0.z + p0.w;
        sc[t] = v;
        mx = fmaxf(mx, v);
    }
#pragma unroll
    for (int off = 32; off > 0; off >>= 1) mx = fmaxf(mx, __shfl_xor(mx, off));
    if (lane == 0) sred[wv] = mx;
    __syncthreads();
    mx = fmaxf(fmaxf(sred[0], sred[1]), fmaxf(sred[2], sred[3]));
    __syncthreads();
    float sum = 0.f;
#pragma unroll
    for (int t = 0; t < 8; ++t) { sc[t] = expf(sc[t] - mx); sum += sc[t]; }
#pragma unroll
    for (int off = 32; off > 0; off >>= 1) sum += __shfl_xor(sum, off);
    if (lane == 0) sred[wv] = sum;
    __syncthreads();
    sum = sred[0] + sred[1] + sred[2] + sred[3];
    float inv = 1.0f / sum;
#pragma unroll
    for (int t = 0; t < 8; ++t)
        weights[(size_t)b * Sn + t * 256 + tid] = sc[t] * inv;
}

// ---------------- context[b,h] = sum_s w[b,s]*keys[b,s,h] ----------------
__global__ __launch_bounds__(256) void context_partial_kernel(
    const float* __restrict__ keys, const float* __restrict__ weights,
    float* __restrict__ cpart)
{
    __shared__ float w[256];
    const int b = blockIdx.x, hb = blockIdx.y, sc = blockIdx.z;
    const int h = hb * 256 + threadIdx.x;
    w[threadIdx.x] = weights[(size_t)b * Sn + sc * 256 + threadIdx.x];
    __syncthreads();
    const float* kp = keys + ((size_t)b * Sn + sc * 256) * Hd + h;
    float acc = 0.f;
#pragma unroll 8
    for (int s = 0; s < 256; ++s)
        acc = fmaf(w[s], kp[(size_t)s * Hd], acc);
    cpart[(size_t)(b * SCH + sc) * Hd + h] = acc;
}

__global__ __launch_bounds__(256) void context_reduce_kernel(
    const float* __restrict__ cpart, float* __restrict__ ctx)
{
    int idx = blockIdx.x * 256 + threadIdx.x;   // 0..32767
    int b = idx >> 10, h = idx & 1023;
    float t = 0.f;
#pragma unroll
    for (int s = 0; s < SCH; ++s) t += cpart[(size_t)(b * SCH + s) * Hd + h];
    ctx[idx] = t;
}

extern "C" void kernel_launch(void* const* d_in, const int* in_sizes, int n_in,
                              void* d_out, int out_size, void* d_ws, size_t ws_size,
                              hipStream_t stream)
{
    const float* query = (const float*)d_in[0];
    const float* keys  = (const float*)d_in[1];
    const float* Wa_w  = (const float*)d_in[2];
    const float* Wa_b  = (const float*)d_in[3];
    const float* Ua_w  = (const float*)d_in[4];
    const float* Ua_b  = (const float*)d_in[5];
    const float* Va_w  = (const float*)d_in[6];
    const float* Va_b  = (const float*)d_in[7];

    float* ctx     = (float*)d_out;            // context: 32*1024
    float* weights = (float*)d_out + Bn * Hd;  // weights: 32*2048

    char* wsb      = (char*)d_ws;
    float* q_proj  = (float*)(wsb + WS_QPROJ);
    float* partial = (float*)(wsb + WS_PARTIAL);
    float* cpart   = (float*)(wsb + WS_CPART);
    unsigned short* ua_hi = (unsigned short*)(wsb + WS_UAHI);
    unsigned short* ua_lo = (unsigned short*)(wsb + WS_UALO);

    const bool use_split = (ws_size >= WS_NEED_SPLIT);  // constant per run

    if (use_split)
        split_kernel<<<dim3(1024), dim3(256), 0, stream>>>(
            (const float4*)Ua_w, (uint2*)ua_hi, (uint2*)ua_lo, (Hd * Hd) / 4);
    qproj_kernel<<<dim3(8192), dim3(256), 0, stream>>>(query, Wa_w, Wa_b, q_proj);
    if (use_split)
        score_gemm_kernel<true><<<dim3(2048), dim3(256), 0, stream>>>(
            keys, ua_hi, ua_lo, Ua_w, Ua_b, Va_w, q_proj, partial);
    else
        score_gemm_kernel<false><<<dim3(2048), dim3(256), 0, stream>>>(
            keys, ua_hi, ua_lo, Ua_w, Ua_b, Va_w, q_proj, partial);
    softmax_kernel<<<dim3(Bn), dim3(256), 0, stream>>>(partial, Va_b, weights);
    context_partial_kernel<<<dim3(Bn, Hd / 256, SCH), dim3(256), 0, stream>>>(
        keys, weights, cpart);
    context_reduce_kernel<<<dim3(128), dim3(256), 0, stream>>>(cpart, ctx);
}